// Round 5
// baseline (165.764 us; speedup 1.0000x reference)
//
#include <hip/hip_runtime.h>
#include <hip/hip_bf16.h>

// TVConv: per-pixel spatially-varying 3x3 depthwise conv.
// x:           (B=8, C=96, H=128, W=128)  fp32
// weight_maps: (1,  C=96, 3, 3, H, W)     fp32
// out:         (B, C, H, W)               fp32
//
// R2/R4 post-mortem: 46us @ 3.0 TB/s with EITHER register or LDS-dest
// staging -> the limiter is bursty short-lived waves (big load burst,
// full drain, brief compute, die), not VGPR-file MLP. m13's 6.3 TB/s
// recipe = many waves, few loads each, steady issue. So: FULL batch
// split -> 1 batch/thread, 12 float4 loads + 1 store per thread, 4x the
// waves, VGPR<=64 for 8 waves/SIMD.
//
// wt is re-read 8x (once per b). Chunked dispatch ordering keeps it L2-
// resident: blockIdx.x = b*S + s (S=256 tiles, 8|S) -> tile s lands on
// XCD s%8 for EVERY b (round-robin heuristic), per-XCD wt working set =
// 32 tiles x 36 KB = 1.15 MB < 4 MB L2, and one chunk (2048 blocks) is
// ~the resident capacity so b-copies run near-concurrently.

namespace {
constexpr int B = 8, C = 96, H = 128, W = 128;
constexpr int HW = H * W;
constexpr int TILES = C * (H / 8);  // 1536 (c, h-octet) tiles; 36 KB wt each
constexpr int S = 256;              // tiles per chunk (divisible by 8)
constexpr int CHUNKS = TILES / S;   // 6
}

__global__ __launch_bounds__(256, 8) void tvconv_kernel(
    const float* __restrict__ x,
    const float* __restrict__ wm,
    float* __restrict__ out) {
  const int t    = threadIdx.x;
  const int s    = blockIdx.x & (S - 1);   // tile-in-chunk
  const int b    = blockIdx.x >> 8;        // batch (S=256)
  const int tile = blockIdx.y * S + s;
  const int c    = tile >> 4;              // 16 h-octets per channel
  const int h    = (tile & 15) * 8 + (t >> 5);
  const int w    = (t & 31) * 4;

  // ---- 9 per-pixel weight float4 loads (L2-hit for 7 of 8 b-passes) ----
  const float* wp = wm + (size_t)c * 9 * HW + h * W + w;
  float4 wt[9];
#pragma unroll
  for (int k = 0; k < 9; ++k) {
    wt[k] = *reinterpret_cast<const float4*>(wp + (size_t)k * HW);
  }

  // ---- 3 x-row float4 loads (zero4 for padded rows) ----
  const float* xb = x + ((size_t)b * C + c) * HW + h * W + w;
  const float4 zero4 = make_float4(0.f, 0.f, 0.f, 0.f);
  float4 xr[3];
  xr[0] = (h > 0)     ? *reinterpret_cast<const float4*>(xb - W) : zero4;
  xr[1] = *reinterpret_cast<const float4*>(xb);
  xr[2] = (h < H - 1) ? *reinterpret_cast<const float4*>(xb + W) : zero4;

  // ---- Compute ----
  const bool at_left  = ((t & 31) == 0);   // w == 0 (lanes 0/32)
  const bool at_right = ((t & 31) == 31);  // w+4 == W (lanes 31/63)
  float acc[4] = {0.f, 0.f, 0.f, 0.f};
#pragma unroll
  for (int i = 0; i < 3; ++i) {
    const float4 ctr = xr[i];
    // Halo via shfl; cross-row pulls at lanes 0/32/31/63 are exactly the
    // padded columns -> masked to 0.
    float left  = __shfl_up(ctr.w, 1);
    float right = __shfl_down(ctr.x, 1);
    if (at_left)  left  = 0.f;
    if (at_right) right = 0.f;
    const float xv[6] = {left, ctr.x, ctr.y, ctr.z, ctr.w, right};
#pragma unroll
    for (int j = 0; j < 3; ++j) {
      const float4 wv = wt[i * 3 + j];
      const float wa[4] = {wv.x, wv.y, wv.z, wv.w};
#pragma unroll
      for (int m = 0; m < 4; ++m) {
        acc[m] += wa[m] * xv[m + j];  // pixel w+m, tap j reads x[w+m+j-1]
      }
    }
  }

  float4 o;
  o.x = acc[0]; o.y = acc[1]; o.z = acc[2]; o.w = acc[3];
  *reinterpret_cast<float4*>(
      out + ((size_t)b * C + c) * HW + h * W + w) = o;
}

extern "C" void kernel_launch(void* const* d_in, const int* in_sizes, int n_in,
                              void* d_out, int out_size, void* d_ws, size_t ws_size,
                              hipStream_t stream) {
  const float* x  = (const float*)d_in[0];
  const float* wm = (const float*)d_in[1];
  float* out = (float*)d_out;

  dim3 grid(S * B, CHUNKS);  // (2048, 6) = 12288 blocks
  tvconv_kernel<<<grid, dim3(256, 1, 1), 0, stream>>>(x, wm, out);
}

// Round 6
// 140.441 us; speedup vs baseline: 1.1803x; 1.1803x over previous
//
#include <hip/hip_runtime.h>
#include <hip/hip_bf16.h>

// TVConv: per-pixel spatially-varying 3x3 depthwise conv.
// x: (8,96,128,128) fp32, wm: (1,96,3,3,128,128) fp32, out: (8,96,128,128).
//
// R1-R5 post-mortem: duration tracks REQUESTED bytes through the VMEM pipe
// (~7-9 TB/s ceiling), not HBM bytes (L3 absorbs re-reads). R2's 46us =
// 314 MB requested (wt x2, x x3, out). This version cuts requests to
// ~170 MB (~= the 157 MB unique footprint):
//   - wt amplification 1x: all 8 batches computed per thread, 9 wt float4
//     in registers, each wt byte requested once device-wide.
//   - x amplification 1.25x: block stages its (c, 10-row, all-8-b) x slab
//     into LDS once via global_load_lds (R4-verified per-lane-pointer
//     form); the 3 vertical taps read LDS (separate pipe), not VMEM.
// Padded rows: staged source row is clamped; compute zero-masks the
// contribution in registers (top_pad/bot_pad), so LDS content for pad
// rows is never used. Halo columns via __shfl, masked at lane 0/31
// boundaries which coincide with W-padding.

namespace {
constexpr int B = 8, C = 96, H = 128, W = 128;
constexpr int HW = H * W;
constexpr int XROWS = 10;            // 8 rows + 2 halo
constexpr int XB = XROWS * W * 4;    // 5120 B per batch slab
}

typedef __attribute__((address_space(1))) void gbl_void;
typedef __attribute__((address_space(3))) void lds_void;

__global__ __launch_bounds__(256, 3) void tvconv_kernel(
    const float* __restrict__ x,
    const float* __restrict__ wm,
    float* __restrict__ out) {
  // 8 slabs x 5120 B = 40960 B + 1024 slack (R3 boundary caution) -> 3 blk/CU.
  __shared__ __align__(16) char xs[B * XB + 1024];

  const int t  = threadIdx.x;
  const int c  = blockIdx.x >> 4;          // 16 h-octets per channel
  const int h0 = (blockIdx.x & 15) * 8;
  const int lr = t >> 5;                   // local row 0..7
  const int w4 = t & 31;
  const int h  = h0 + lr;
  const int w  = w4 * 4;

  // ---- Stage x slab: 2560 float4 (8 b x 10 rows x 32), 10 per thread ----
  // LDS layout [b][r][col] is linear in i = k*256+t -> dst = xs + i*16,
  // which satisfies the wave-uniform-base + lane*16 rule automatically.
#pragma unroll
  for (int k = 0; k < 10; ++k) {
    const int i   = k * 256 + t;
    const int b   = i / 320;               // slab
    const int rem = i - b * 320;
    const int r   = rem >> 5;              // row-in-slab 0..9
    const int col = rem & 31;              // float4-in-row
    int row = h0 - 1 + r;                  // global row; clamp (masked later)
    row = min(max(row, 0), H - 1);
    const float* src = x + ((size_t)(b * C + c)) * HW + row * W + col * 4;
    __builtin_amdgcn_global_load_lds((const gbl_void*)src,
                                     (lds_void*)(xs + i * 16), 16, 0, 0);
  }

  // ---- 9 per-pixel weights into registers (requested ONCE device-wide) ----
  const float* wp = wm + (size_t)c * 9 * HW + h * W + w;
  float4 wt[9];
#pragma unroll
  for (int k = 0; k < 9; ++k) {
    wt[k] = *reinterpret_cast<const float4*>(wp + (size_t)k * HW);
  }

  __syncthreads();  // drains vmcnt (global_load_lds) + makes LDS visible

  // ---- Compute: all 8 batches from LDS ----
  const bool at_left  = (w4 == 0);
  const bool at_right = (w4 == 31);
  const bool top_pad  = (h == 0);          // tap i=0 is padding
  const bool bot_pad  = (h == H - 1);      // tap i=2 is padding
  const float4 zero4 = make_float4(0.f, 0.f, 0.f, 0.f);

#pragma unroll
  for (int b = 0; b < B; ++b) {
    float acc[4] = {0.f, 0.f, 0.f, 0.f};
#pragma unroll
    for (int i = 0; i < 3; ++i) {
      // LDS row lr+i holds global row h0-1+(lr+i) = h+i-1 (clamped copy).
      float4 ctr = *reinterpret_cast<const float4*>(
          xs + b * XB + (lr + i) * 512 + w4 * 16);
      const bool pad = (i == 0 && top_pad) || (i == 2 && bot_pad);
      if (pad) ctr = zero4;
      float left  = __shfl_up(ctr.w, 1);
      float right = __shfl_down(ctr.x, 1);
      if (at_left)  left  = 0.f;   // lanes 0/32: w==0 (cross-row pull masked)
      if (at_right) right = 0.f;   // lanes 31/63: w+4==W
      const float xv[6] = {left, ctr.x, ctr.y, ctr.z, ctr.w, right};
#pragma unroll
      for (int j = 0; j < 3; ++j) {
        const float4 wv = wt[i * 3 + j];
        const float wa[4] = {wv.x, wv.y, wv.z, wv.w};
#pragma unroll
        for (int m = 0; m < 4; ++m) {
          acc[m] += wa[m] * xv[m + j];  // pixel w+m, tap j reads x[w+m+j-1]
        }
      }
    }
    float4 o;
    o.x = acc[0]; o.y = acc[1]; o.z = acc[2]; o.w = acc[3];
    *reinterpret_cast<float4*>(
        out + ((size_t)(b * C + c)) * HW + h * W + w) = o;
  }
}

extern "C" void kernel_launch(void* const* d_in, const int* in_sizes, int n_in,
                              void* d_out, int out_size, void* d_ws, size_t ws_size,
                              hipStream_t stream) {
  const float* x  = (const float*)d_in[0];
  const float* wm = (const float*)d_in[1];
  float* out = (float*)d_out;

  const int blocks = C * (H / 8);  // 1536
  tvconv_kernel<<<blocks, 256, 0, stream>>>(x, wm, out);
}